// Round 10
// baseline (324.200 us; speedup 1.0000x reference)
//
#include <hip/hip_runtime.h>

typedef __bf16 bf16x8 __attribute__((ext_vector_type(8)));
typedef float  floatx4 __attribute__((ext_vector_type(4)));

constexpr int B_    = 2048;
constexpr int NIN   = 256;
constexpr int H_    = 128;
constexpr int RANK_ = 8;
constexpr float EPS_ = 1e-5f;

// ---------------------------------------------------------------------------
// HEAD: zero stats; in_proj on blocks with bx&3==0 (8 rows, W LDS-staged);
// pconv on all 1024 blocks (1 p-unit, fp32 LDS transpose). Grid 1024 x 256.
__global__ __launch_bounds__(256)
void k_head(const float* __restrict__ X,
            const float* __restrict__ W1, const float* __restrict__ b1,
            const float* __restrict__ W2, const float* __restrict__ b2,
            const float* __restrict__ P,
            float* __restrict__ Z, float* __restrict__ R2, __bf16* __restrict__ Zbf,
            __bf16* __restrict__ Pperm, float* __restrict__ stats /* 9*256 */) {
    __shared__ float smem[10240];            // 40 KB: sX[2048]|sW1[4096]|sW2[4096]; pconv reuses
    const int bx = blockIdx.x, t = threadIdx.x;

    if (bx < RANK_ + 1) stats[bx * 256 + t] = 0.f;

    if ((bx & 3) == 0) {   // in_proj: rows (bx>>2)*8 .. +8, W staged via LDS
        const int b0 = (bx >> 2) * 8;
        float* sX  = smem;
        float* sW1 = smem + 2048;
        float* sW2 = smem + 6144;
        for (int e = t; e < 2048; e += 256) {
            const int row = e >> 8, i = e & 255;
            sX[e] = X[(size_t)(b0 + row) * NIN + i];
        }
        const int col = t & 127, rh = t >> 7;
        float s1[4] = {0.f, 0.f, 0.f, 0.f}, s2[4] = {0.f, 0.f, 0.f, 0.f};
        for (int c = 0; c < 8; ++c) {
            __syncthreads();
#pragma unroll
            for (int q = 0; q < 4; ++q) {    // stage 32 i-rows of W1,W2 (float4)
                const int idx = q * 256 + t;
                const int i = idx >> 5, c4 = idx & 31;
                *(float4*)&sW1[i * 128 + c4 * 4] =
                    *(const float4*)&W1[(size_t)(c * 32 + i) * H_ + c4 * 4];
                *(float4*)&sW2[i * 128 + c4 * 4] =
                    *(const float4*)&W2[(size_t)(c * 32 + i) * H_ + c4 * 4];
            }
            __syncthreads();
#pragma unroll 4
            for (int i = 0; i < 32; ++i) {
                const float w1 = sW1[i * 128 + col];
                const float w2 = sW2[i * 128 + col];
#pragma unroll
                for (int j = 0; j < 4; ++j) {
                    const float x = sX[(rh * 4 + j) * 256 + c * 32 + i];
                    s1[j] = fmaf(x, w1, s1[j]);
                    s2[j] = fmaf(x, w2, s2[j]);
                }
            }
        }
#pragma unroll
        for (int j = 0; j < 4; ++j) {
            const int b = b0 + rh * 4 + j;
            const float z = fmaxf(s1[j] + b1[col], 0.f);
            const float r = fmaxf(s2[j] + b2[col], 0.f);
            Z[(size_t)b * H_ + col]   = z;
            Zbf[(size_t)b * H_ + col] = (__bf16)z;
            R2[(size_t)b * H_ + col]  = r;
        }
        __syncthreads();
    }
    {   // pconv: unit = bx -> (rank r, p); Pperm (r, kg)-contiguous slices
        float* sT = smem;                    // 32*129 floats
        const int r = bx >> 7, p = bx & 127;
        const float4* Pp4 = (const float4*)(P + ((size_t)r * H_ + p) * (H_ * H_));
        __bf16* dst = Pperm + (size_t)r * (H_ * H_ * H_);
        const int L = t & 63, quad = L >> 4, lo = L & 15, g0 = t >> 6;
#pragma unroll
        for (int s = 0; s < 4; ++s) {
#pragma unroll
            for (int it = 0; it < 4; ++it) {
                const int idx = it * 256 + t;
                const int q = idx >> 5, k4 = idx & 31;
                const float4 v = Pp4[(size_t)(s * 32 + q) * 32 + k4];
                float* d = sT + q * 129 + k4 * 4;
                d[0] = v.x; d[1] = v.y; d[2] = v.z; d[3] = v.w;
            }
            __syncthreads();
#pragma unroll
            for (int gg = 0; gg < 2; ++gg) {
                const int g = g0 + 4 * gg;
                __bf16 v8[8];
#pragma unroll
                for (int j = 0; j < 8; ++j)
                    v8[j] = (__bf16)sT[(quad * 8 + j) * 129 + g * 16 + lo];
                *(bf16x8*)(dst + (((size_t)(g * 128 + p) * 4 + s) * 64 + L) * 8) =
                    *(const bf16x8*)v8;
            }
            __syncthreads();
        }
    }
}

// ---------------------------------------------------------------------------
// RANK r: T_r = sum_p BNprev(prevT)[:,p] * (Zbf @ P_r[p]); stats_r; Y accum.
// Grid (8 kg, 32 m) -> XCD = kg. 1024 thr (16 waves, 4/SIMD, 1 block/CU).
// Wave w owns p in [w*8, w*8+8) x all 4 m-tiles: B read once per block.
// ymode: 0 none (rank0), 1 Y=val/8 (rank1), 2 Y+=val/8 (ranks 2..7), kg==0 only.
__global__ __launch_bounds__(1024, 1)
void k_rank(const __bf16* __restrict__ Pr, const __bf16* __restrict__ Zbf,
            const float* __restrict__ prevT, const float* __restrict__ prevStats,
            const float* __restrict__ gz, const float* __restrict__ bz,
            float* __restrict__ T, float* __restrict__ stats,
            float* __restrict__ Y, const int ymode) {
    __shared__ float smem[16672];    // sZin[128][68] / reduce[16*1024] | sAl,sBe,cs
    const int kg = blockIdx.x, mblk = blockIdx.y, b0 = mblk * 64;
    const int t = threadIdx.x;
    const int w = t >> 6, L = t & 63, quad = L >> 4, lo = L & 15;

    float* sAl = smem + 16384; float* sBe = smem + 16512;
    if (t < 128) {
        if (ymode == 0) { sAl[t] = 1.f; sBe[t] = 0.f; }
        else {
            const float s1 = prevStats[t], s2 = prevStats[128 + t];
            const float mm = s1 * (1.f / B_);
            const float var = s2 * (1.f / B_) - mm * mm;
            const float a = rsqrtf(var + EPS_) * gz[t];
            sAl[t] = a; sBe[t] = bz[t] - mm * a;
        }
    }
    // A-frags: 64 rows x K=128, rank-invariant (64 VGPRs)
    bf16x8 A[4][4];
#pragma unroll
    for (int mt = 0; mt < 4; ++mt)
#pragma unroll
        for (int ks = 0; ks < 4; ++ks)
            A[mt][ks] = *(const bf16x8*)(Zbf + (size_t)(b0 + mt * 16 + lo) * H_ + ks * 32 + quad * 8);
    __syncthreads();
    {   // stage normalized Zin -> sZin[p][row] (stride 68); Y accum (kg==0)
        const int sp = t & 127, rr = t >> 7;     // col, row-eighth
        const float a = sAl[sp], be = sBe[sp];
#pragma unroll
        for (int i = 0; i < 8; ++i) {
            const int row = rr + 8 * i;
            const float zin = fmaf(prevT[(size_t)(b0 + row) * H_ + sp], a, be);
            smem[sp * 68 + row] = zin;
            if (kg == 0 && ymode != 0) {
                float* yp = Y + (size_t)(b0 + row) * H_ + sp;
                *yp = (ymode == 1) ? zin * (1.f / RANK_) : fmaf(zin, 1.f / RANK_, *yp);
            }
        }
    }
    __syncthreads();

    floatx4 acc[4];
#pragma unroll
    for (int mt = 0; mt < 4; ++mt) acc[mt] = (floatx4){0.f, 0.f, 0.f, 0.f};

    const bf16x8* Pb = (const bf16x8*)Pr;
    const size_t wb = ((size_t)kg * 128 + w * 8) * 4;
    for (int pp = 0; pp < 8; ++pp) {
        bf16x8 Bf[4];
#pragma unroll
        for (int s = 0; s < 4; ++s)
            Bf[s] = Pb[(wb + (size_t)pp * 4 + s) * 64 + L];
        const int p = w * 8 + pp;
#pragma unroll
        for (int mt = 0; mt < 4; ++mt) {
            floatx4 S = (floatx4){0.f, 0.f, 0.f, 0.f};
#pragma unroll
            for (int ks = 0; ks < 4; ++ks)
                S = __builtin_amdgcn_mfma_f32_16x16x32_bf16(A[mt][ks], Bf[ks], S, 0, 0, 0);
            const floatx4 zi = *(const floatx4*)&smem[p * 68 + mt * 16 + quad * 4];
            acc[mt] += zi * S;
        }
    }
    __syncthreads();                 // sZin dead; reuse for cross-wave p-reduce
#pragma unroll
    for (int mt = 0; mt < 4; ++mt)
#pragma unroll
        for (int i = 0; i < 4; ++i)
            smem[w * 1024 + (mt * 4 + i) * 64 + L] = acc[mt][i];
    if (t < 32) smem[16640 + t] = 0.f;
    __syncthreads();

    // one output element per thread
    float v = 0.f;
#pragma unroll
    for (int q = 0; q < 16; ++q) v += smem[q * 1024 + t];
    const int j = t >> 6, L2 = t & 63;
    const int row = b0 + (j >> 2) * 16 + (L2 >> 4) * 4 + (j & 3);
    const int col = kg * 16 + (L2 & 15);
    T[(size_t)row * H_ + col] = v;
    float cs = v, cs2 = v * v;
    cs  += __shfl_xor(cs, 16);  cs  += __shfl_xor(cs, 32);
    cs2 += __shfl_xor(cs2, 16); cs2 += __shfl_xor(cs2, 32);
    if (L2 < 16) { atomicAdd(&smem[16640 + L2], cs); atomicAdd(&smem[16656 + L2], cs2); }
    __syncthreads();
    if (t < 16)      atomicAdd(&stats[kg * 16 + t],            smem[16640 + t]);
    else if (t < 32) atomicAdd(&stats[128 + kg * 16 + t - 16], smem[16640 + t]);
}

// ---------------------------------------------------------------------------
// Y += BN_7(T_7)/8 (finalize); ystats. Grid 64 x 256.
__global__ __launch_bounds__(256)
void k_y(const float* __restrict__ T7, const float* __restrict__ s7,
         const float* __restrict__ gz, const float* __restrict__ bz,
         float* __restrict__ Y, float* __restrict__ ysums) {
    __shared__ float sAl[128], sBe[128], red[256];
    const int bx = blockIdx.x, t = threadIdx.x;
    if (t < 128) {
        const float s1 = s7[t], s2 = s7[128 + t];
        const float mm = s1 * (1.f / B_);
        const float var = s2 * (1.f / B_) - mm * mm;
        const float a = rsqrtf(var + EPS_) * gz[t];
        sAl[t] = a; sBe[t] = bz[t] - mm * a;
    }
    red[t] = 0.f;
    __syncthreads();
    const int col = t & 127, half = t >> 7;
    const float a = sAl[col], be = sBe[col];
    float ps = 0.f, ps2 = 0.f;
    for (int i = 0; i < 16; ++i) {
        const int b = bx * 32 + half + 2 * i;
        const size_t gi = (size_t)b * H_ + col;
        const float y = Y[gi] + fmaf(T7[gi], a, be) * (1.f / RANK_);
        Y[gi] = y;
        ps += y; ps2 += y * y;
    }
    atomicAdd(&red[col],       half == 0 ? ps  : 0.f);
    atomicAdd(&red[128 + col], half == 0 ? ps2 : 0.f);
    __syncthreads();
    atomicAdd(&red[col],       half == 1 ? ps  : 0.f);
    atomicAdd(&red[128 + col], half == 1 ? ps2 : 0.f);
    __syncthreads();
    if (t < 128) {
        atomicAdd(&ysums[t],       red[t]);
        atomicAdd(&ysums[128 + t], red[128 + t]);
    }
}

// ---------------------------------------------------------------------------
// out = relu(relu(BN(Y)@W3 + b3) + R2). Grid 256 x 256, 8 rows per block.
__global__ __launch_bounds__(256)
void k_out(const float* __restrict__ Y, const float* __restrict__ ystats,
           const float* __restrict__ gy, const float* __restrict__ by,
           const float* __restrict__ W3, const float* __restrict__ b3,
           const float* __restrict__ R2, float* __restrict__ out) {
    __shared__ float sy[8 * 132];
    const int bx = blockIdx.x, t = threadIdx.x;
    const int col = t & 127, rh = t >> 7;
    const int b0 = bx * 8;
    const float mm = ystats[col] * (1.f / B_);
    const float var = ystats[128 + col] * (1.f / B_) - mm * mm;
    const float ay = rsqrtf(var + EPS_) * gy[col];
    const float bb = by[col] - mm * ay;
#pragma unroll
    for (int i = 0; i < 4; ++i) {
        const int row = rh + 2 * i;
        sy[row * 132 + col] = fmaf(Y[(size_t)(b0 + row) * H_ + col], ay, bb);
    }
    __syncthreads();
#pragma unroll
    for (int j = 0; j < 4; ++j) {
        const int row = rh * 4 + j;
        float s = 0.f;
        const float* syr = sy + row * 132;
#pragma unroll 8
        for (int h = 0; h < H_; ++h)
            s = fmaf(syr[h], W3[h * H_ + col], s);
        const size_t gi = (size_t)(b0 + row) * H_ + col;
        out[gi] = fmaxf(fmaxf(s + b3[col], 0.f) + R2[gi], 0.f);
    }
}

// ---------------------------------------------------------------------------
extern "C" void kernel_launch(void* const* d_in, const int* in_sizes, int n_in,
                              void* d_out, int out_size, void* d_ws, size_t ws_size,
                              hipStream_t stream) {
    const float* X  = (const float*)d_in[0];
    const float* W1 = (const float*)d_in[1];
    const float* b1 = (const float*)d_in[2];
    const float* W2 = (const float*)d_in[3];
    const float* b2 = (const float*)d_in[4];
    const float* W3 = (const float*)d_in[5];
    const float* b3 = (const float*)d_in[6];
    const float* P  = (const float*)d_in[7];
    const float* gz = (const float*)d_in[8];
    const float* bz = (const float*)d_in[9];
    const float* gy = (const float*)d_in[10];
    const float* by = (const float*)d_in[11];
    float* out = (float*)d_out;

    const size_t rankElems = (size_t)H_ * H_ * H_;

    char* wsb = (char*)d_ws;
    float* Z      = (float*)wsb;   wsb += (size_t)B_ * H_ * 4;
    float* R2     = (float*)wsb;   wsb += (size_t)B_ * H_ * 4;
    float* Y      = (float*)wsb;   wsb += (size_t)B_ * H_ * 4;
    float* stats  = (float*)wsb;   wsb += (size_t)(RANK_ + 1) * 256 * 4;  // sums | ysums
    float* T      = (float*)wsb;   wsb += (size_t)RANK_ * B_ * H_ * 4;
    __bf16* Zbf   = (__bf16*)wsb;  wsb += (size_t)B_ * H_ * 2;
    __bf16* Pperm = (__bf16*)wsb;

    float* ysums = stats + RANK_ * 256;

    k_head<<<1024, 256, 0, stream>>>(X, W1, b1, W2, b2, P, Z, R2, Zbf, Pperm, stats);

    for (int r = 0; r < RANK_; ++r) {
        const float* prevT = (r == 0) ? Z : (T + (size_t)(r - 1) * B_ * H_);
        const float* prevS = (r == 0) ? stats : (stats + (r - 1) * 256);
        const int ymode = (r == 0) ? 0 : (r == 1 ? 1 : 2);
        k_rank<<<dim3(8, 32), 1024, 0, stream>>>(Pperm + (size_t)r * rankElems, Zbf,
                                                 prevT, prevS, gz, bz,
                                                 T + (size_t)r * B_ * H_, stats + r * 256,
                                                 Y, ymode);
    }

    k_y<<<64, 256, 0, stream>>>(T + (size_t)7 * B_ * H_, stats + 7 * 256, gz, bz, Y, ysums);
    k_out<<<256, 256, 0, stream>>>(Y, ysums, gy, by, W3, b3, R2, out);
}

// Round 11
// 317.750 us; speedup vs baseline: 1.0203x; 1.0203x over previous
//
#include <hip/hip_runtime.h>

typedef __bf16 bf16x8 __attribute__((ext_vector_type(8)));
typedef float  floatx4 __attribute__((ext_vector_type(4)));

constexpr int B_    = 2048;
constexpr int NIN   = 256;
constexpr int H_    = 128;
constexpr int RANK_ = 8;
constexpr float EPS_ = 1e-5f;

// ---------------------------------------------------------------------------
// HEAD: zero stats; in_proj (4 rows/block); pconv of RANK 0 ONLY (one s-chunk
// per block: 512 units). Grid 512 x 256.
__global__ __launch_bounds__(256)
void k_head(const float* __restrict__ X,
            const float* __restrict__ W1, const float* __restrict__ b1,
            const float* __restrict__ W2, const float* __restrict__ b2,
            const float* __restrict__ P,
            float* __restrict__ Z, float* __restrict__ R2, __bf16* __restrict__ Zbf,
            __bf16* __restrict__ Pperm, float* __restrict__ stats /* 9*256 */) {
    __shared__ float smem[4160];             // sx[1024] / sT[32*129]
    const int bx = blockIdx.x, t = threadIdx.x;

    if (bx < RANK_ + 1) stats[bx * 256 + t] = 0.f;

    {   // in_proj rows bx*4 .. +4; thread (col, rh) does rows rh, rh+2
        const int b0 = bx * 4;
#pragma unroll
        for (int i = 0; i < 4; ++i) {
            const int e = i * 256 + t;
            smem[e] = X[(size_t)(b0 + (e >> 8)) * NIN + (e & 255)];
        }
        __syncthreads();
        const int col = t & 127, rh = t >> 7;
        float s1a = 0.f, s2a = 0.f, s1b = 0.f, s2b = 0.f;
        const float* sxa = smem + rh * 256;
        const float* sxb = smem + (rh + 2) * 256;
#pragma unroll 8
        for (int i = 0; i < NIN; ++i) {
            const float w1 = W1[i * H_ + col];
            const float w2 = W2[i * H_ + col];
            s1a = fmaf(sxa[i], w1, s1a);  s2a = fmaf(sxa[i], w2, s2a);
            s1b = fmaf(sxb[i], w1, s1b);  s2b = fmaf(sxb[i], w2, s2b);
        }
        const int ba = b0 + rh, bb = b0 + rh + 2;
        const float za = fmaxf(s1a + b1[col], 0.f), ra = fmaxf(s2a + b2[col], 0.f);
        const float zb = fmaxf(s1b + b1[col], 0.f), rb = fmaxf(s2b + b2[col], 0.f);
        Z[(size_t)ba * H_ + col] = za;  Zbf[(size_t)ba * H_ + col] = (__bf16)za;
        R2[(size_t)ba * H_ + col] = ra;
        Z[(size_t)bb * H_ + col] = zb;  Zbf[(size_t)bb * H_ + col] = (__bf16)zb;
        R2[(size_t)bb * H_ + col] = rb;
        __syncthreads();
    }
    {   // pconv rank 0: unit = bx -> (p = bx>>2, s = bx&3)
        const int p = bx >> 2, s = bx & 3;
        const float4* Pp4 = (const float4*)(P + (size_t)p * (H_ * H_));
        const int L = t & 63, quad = L >> 4, lo = L & 15, g0 = t >> 6;
#pragma unroll
        for (int it = 0; it < 4; ++it) {     // 32 q-rows x 128 k, coalesced
            const int idx = it * 256 + t;
            const int q = idx >> 5, k4 = idx & 31;
            const float4 v = Pp4[(size_t)(s * 32 + q) * 32 + k4];
            float* d = smem + q * 129 + k4 * 4;
            d[0] = v.x; d[1] = v.y; d[2] = v.z; d[3] = v.w;
        }
        __syncthreads();
#pragma unroll
        for (int gg = 0; gg < 2; ++gg) {     // conflict-free reads, cvt, emit
            const int g = g0 + 4 * gg;
            __bf16 v8[8];
#pragma unroll
            for (int j = 0; j < 8; ++j)
                v8[j] = (__bf16)smem[(quad * 8 + j) * 129 + g * 16 + lo];
            *(bf16x8*)(Pperm + (((size_t)(g * 128 + p) * 4 + s) * 64 + L) * 8) =
                *(const bf16x8*)v8;
        }
    }
}

// ---------------------------------------------------------------------------
// RANK r: T_r = sum_p BNprev(prevT)[:,p] * (Zbf @ P_r[p]); stats_r; Y accum;
// tail: permute rank r+1's P slice (doPconv). Grid (8 kg, 32 m) -> XCD = kg.
// 1024 thr (16 waves, 4/SIMD). Wave w owns p in [w*8,w*8+8) x all 4 m-tiles.
__global__ __launch_bounds__(1024, 1)
void k_rank(const __bf16* __restrict__ Pr, const __bf16* __restrict__ Zbf,
            const float* __restrict__ prevT, const float* __restrict__ prevStats,
            const float* __restrict__ gz, const float* __restrict__ bz,
            float* __restrict__ T, float* __restrict__ stats,
            float* __restrict__ Y, const int ymode,
            const float* __restrict__ Pnext, __bf16* __restrict__ PpermNext,
            const int doPconv) {
    __shared__ float smem[16672];    // sZin[128][68] / reduce[16*1024] | sAl,sBe,cs
    const int kg = blockIdx.x, mblk = blockIdx.y, b0 = mblk * 64;
    const int t = threadIdx.x;
    const int w = t >> 6, L = t & 63, quad = L >> 4, lo = L & 15;

    float* sAl = smem + 16384; float* sBe = smem + 16512;
    if (t < 128) {
        if (ymode == 0) { sAl[t] = 1.f; sBe[t] = 0.f; }
        else {
            const float s1 = prevStats[t], s2 = prevStats[128 + t];
            const float mm = s1 * (1.f / B_);
            const float var = s2 * (1.f / B_) - mm * mm;
            const float a = rsqrtf(var + EPS_) * gz[t];
            sAl[t] = a; sBe[t] = bz[t] - mm * a;
        }
    }
    // A-frags: 64 rows x K=128, rank-invariant (64 VGPRs)
    bf16x8 A[4][4];
#pragma unroll
    for (int mt = 0; mt < 4; ++mt)
#pragma unroll
        for (int ks = 0; ks < 4; ++ks)
            A[mt][ks] = *(const bf16x8*)(Zbf + (size_t)(b0 + mt * 16 + lo) * H_ + ks * 32 + quad * 8);
    __syncthreads();
    {   // stage normalized Zin -> sZin[p][row] (stride 68); Y accum (kg==0)
        const int sp = t & 127, rr = t >> 7;     // col, row-eighth
        const float a = sAl[sp], be = sBe[sp];
#pragma unroll
        for (int i = 0; i < 8; ++i) {
            const int row = rr + 8 * i;
            const float zin = fmaf(prevT[(size_t)(b0 + row) * H_ + sp], a, be);
            smem[sp * 68 + row] = zin;
            if (kg == 0 && ymode != 0) {
                float* yp = Y + (size_t)(b0 + row) * H_ + sp;
                *yp = (ymode == 1) ? zin * (1.f / RANK_) : fmaf(zin, 1.f / RANK_, *yp);
            }
        }
    }
    __syncthreads();

    floatx4 acc[4];
#pragma unroll
    for (int mt = 0; mt < 4; ++mt) acc[mt] = (floatx4){0.f, 0.f, 0.f, 0.f};

    const bf16x8* Pb = (const bf16x8*)Pr;
    const size_t wb = ((size_t)kg * 128 + w * 8) * 4;
    for (int pp = 0; pp < 8; ++pp) {
        bf16x8 Bf[4];
#pragma unroll
        for (int s = 0; s < 4; ++s)
            Bf[s] = Pb[(wb + (size_t)pp * 4 + s) * 64 + L];
        const int p = w * 8 + pp;
#pragma unroll
        for (int mt = 0; mt < 4; ++mt) {
            floatx4 S = (floatx4){0.f, 0.f, 0.f, 0.f};
#pragma unroll
            for (int ks = 0; ks < 4; ++ks)
                S = __builtin_amdgcn_mfma_f32_16x16x32_bf16(A[mt][ks], Bf[ks], S, 0, 0, 0);
            const floatx4 zi = *(const floatx4*)&smem[p * 68 + mt * 16 + quad * 4];
            acc[mt] += zi * S;
        }
    }
    __syncthreads();                 // sZin dead; reuse for cross-wave p-reduce
#pragma unroll
    for (int mt = 0; mt < 4; ++mt)
#pragma unroll
        for (int i = 0; i < 4; ++i)
            smem[w * 1024 + (mt * 4 + i) * 64 + L] = acc[mt][i];
    if (t < 32) smem[16640 + t] = 0.f;
    __syncthreads();

    // one output element per thread
    float v = 0.f;
#pragma unroll
    for (int q = 0; q < 16; ++q) v += smem[q * 1024 + t];
    const int j = t >> 6, L2 = t & 63;
    const int row = b0 + (j >> 2) * 16 + (L2 >> 4) * 4 + (j & 3);
    const int col = kg * 16 + (L2 & 15);
    T[(size_t)row * H_ + col] = v;
    float cs = v, cs2 = v * v;
    cs  += __shfl_xor(cs, 16);  cs  += __shfl_xor(cs, 32);
    cs2 += __shfl_xor(cs2, 16); cs2 += __shfl_xor(cs2, 32);
    if (L2 < 16) { atomicAdd(&smem[16640 + L2], cs); atomicAdd(&smem[16656 + L2], cs2); }
    __syncthreads();
    if (t < 16)      atomicAdd(&stats[kg * 16 + t],            smem[16640 + t]);
    else if (t < 32) atomicAdd(&stats[128 + kg * 16 + t - 16], smem[16640 + t]);

    // ===== tail: permute next rank's P slice (2 s-chunks per block) =====
    if (doPconv) {
        const int lid = kg * 32 + mblk;          // 0..255
        const int p = lid >> 1;
        const int s0 = (lid & 1) << 1;
        const float4* Pp4 = (const float4*)(Pnext + (size_t)p * (H_ * H_));
        const int q = t >> 5, k4 = t & 31;       // 1024 thr = 32q x 32k4
        for (int ss = 0; ss < 2; ++ss) {
            const int s = s0 + ss;
            const float4 vv = Pp4[(size_t)(s * 32 + q) * 32 + k4];
            __syncthreads();                     // prior smem reads complete
            float* d = smem + q * 129 + k4 * 4;
            d[0] = vv.x; d[1] = vv.y; d[2] = vv.z; d[3] = vv.w;
            __syncthreads();
            if (w < 8) {                         // waves 0..7 emit g = w
                __bf16 v8[8];
#pragma unroll
                for (int jj = 0; jj < 8; ++jj)
                    v8[jj] = (__bf16)smem[(quad * 8 + jj) * 129 + w * 16 + lo];
                *(bf16x8*)(PpermNext + (((size_t)(w * 128 + p) * 4 + s) * 64 + L) * 8) =
                    *(const bf16x8*)v8;
            }
        }
    }
}

// ---------------------------------------------------------------------------
// Y += BN_7(T_7)/8 (finalize); ystats. Grid 64 x 256.
__global__ __launch_bounds__(256)
void k_y(const float* __restrict__ T7, const float* __restrict__ s7,
         const float* __restrict__ gz, const float* __restrict__ bz,
         float* __restrict__ Y, float* __restrict__ ysums) {
    __shared__ float sAl[128], sBe[128], red[256];
    const int bx = blockIdx.x, t = threadIdx.x;
    if (t < 128) {
        const float s1 = s7[t], s2 = s7[128 + t];
        const float mm = s1 * (1.f / B_);
        const float var = s2 * (1.f / B_) - mm * mm;
        const float a = rsqrtf(var + EPS_) * gz[t];
        sAl[t] = a; sBe[t] = bz[t] - mm * a;
    }
    red[t] = 0.f;
    __syncthreads();
    const int col = t & 127, half = t >> 7;
    const float a = sAl[col], be = sBe[col];
    float ps = 0.f, ps2 = 0.f;
    for (int i = 0; i < 16; ++i) {
        const int b = bx * 32 + half + 2 * i;
        const size_t gi = (size_t)b * H_ + col;
        const float y = Y[gi] + fmaf(T7[gi], a, be) * (1.f / RANK_);
        Y[gi] = y;
        ps += y; ps2 += y * y;
    }
    atomicAdd(&red[col],       half == 0 ? ps  : 0.f);
    atomicAdd(&red[128 + col], half == 0 ? ps2 : 0.f);
    __syncthreads();
    atomicAdd(&red[col],       half == 1 ? ps  : 0.f);
    atomicAdd(&red[128 + col], half == 1 ? ps2 : 0.f);
    __syncthreads();
    if (t < 128) {
        atomicAdd(&ysums[t],       red[t]);
        atomicAdd(&ysums[128 + t], red[128 + t]);
    }
}

// ---------------------------------------------------------------------------
// out = relu(relu(BN(Y)@W3 + b3) + R2). Grid 256 x 256, 8 rows per block.
__global__ __launch_bounds__(256)
void k_out(const float* __restrict__ Y, const float* __restrict__ ystats,
           const float* __restrict__ gy, const float* __restrict__ by,
           const float* __restrict__ W3, const float* __restrict__ b3,
           const float* __restrict__ R2, float* __restrict__ out) {
    __shared__ float sy[8 * 132];
    const int bx = blockIdx.x, t = threadIdx.x;
    const int col = t & 127, rh = t >> 7;
    const int b0 = bx * 8;
    const float mm = ystats[col] * (1.f / B_);
    const float var = ystats[128 + col] * (1.f / B_) - mm * mm;
    const float ay = rsqrtf(var + EPS_) * gy[col];
    const float bb = by[col] - mm * ay;
#pragma unroll
    for (int i = 0; i < 4; ++i) {
        const int row = rh + 2 * i;
        sy[row * 132 + col] = fmaf(Y[(size_t)(b0 + row) * H_ + col], ay, bb);
    }
    __syncthreads();
#pragma unroll
    for (int j = 0; j < 4; ++j) {
        const int row = rh * 4 + j;
        float s = 0.f;
        const float* syr = sy + row * 132;
#pragma unroll 8
        for (int h = 0; h < H_; ++h)
            s = fmaf(syr[h], W3[h * H_ + col], s);
        const size_t gi = (size_t)(b0 + row) * H_ + col;
        out[gi] = fmaxf(fmaxf(s + b3[col], 0.f) + R2[gi], 0.f);
    }
}

// ---------------------------------------------------------------------------
extern "C" void kernel_launch(void* const* d_in, const int* in_sizes, int n_in,
                              void* d_out, int out_size, void* d_ws, size_t ws_size,
                              hipStream_t stream) {
    const float* X  = (const float*)d_in[0];
    const float* W1 = (const float*)d_in[1];
    const float* b1 = (const float*)d_in[2];
    const float* W2 = (const float*)d_in[3];
    const float* b2 = (const float*)d_in[4];
    const float* W3 = (const float*)d_in[5];
    const float* b3 = (const float*)d_in[6];
    const float* P  = (const float*)d_in[7];
    const float* gz = (const float*)d_in[8];
    const float* bz = (const float*)d_in[9];
    const float* gy = (const float*)d_in[10];
    const float* by = (const float*)d_in[11];
    float* out = (float*)d_out;

    const size_t rankElems = (size_t)H_ * H_ * H_;

    char* wsb = (char*)d_ws;
    float* Z      = (float*)wsb;   wsb += (size_t)B_ * H_ * 4;
    float* R2     = (float*)wsb;   wsb += (size_t)B_ * H_ * 4;
    float* Y      = (float*)wsb;   wsb += (size_t)B_ * H_ * 4;
    float* stats  = (float*)wsb;   wsb += (size_t)(RANK_ + 1) * 256 * 4;  // sums | ysums
    float* T      = (float*)wsb;   wsb += (size_t)RANK_ * B_ * H_ * 4;
    __bf16* Zbf   = (__bf16*)wsb;  wsb += (size_t)B_ * H_ * 2;
    __bf16* Pperm = (__bf16*)wsb;

    float* ysums = stats + RANK_ * 256;

    k_head<<<512, 256, 0, stream>>>(X, W1, b1, W2, b2, P, Z, R2, Zbf, Pperm, stats);

    for (int r = 0; r < RANK_; ++r) {
        const float* prevT = (r == 0) ? Z : (T + (size_t)(r - 1) * B_ * H_);
        const float* prevS = (r == 0) ? stats : (stats + (r - 1) * 256);
        const int ymode = (r == 0) ? 0 : (r == 1 ? 1 : 2);
        const int doP = (r < RANK_ - 1) ? 1 : 0;
        k_rank<<<dim3(8, 32), 1024, 0, stream>>>(Pperm + (size_t)r * rankElems, Zbf,
                                                 prevT, prevS, gz, bz,
                                                 T + (size_t)r * B_ * H_, stats + r * 256,
                                                 Y, ymode,
                                                 P + (size_t)(r + 1) * rankElems,
                                                 Pperm + (size_t)(r + 1) * rankElems,
                                                 doP);
    }

    k_y<<<64, 256, 0, stream>>>(T + (size_t)7 * B_ * H_, stats + 7 * 256, gz, bz, Y, ysums);
    k_out<<<256, 256, 0, stream>>>(Y, ysums, gy, by, W3, b3, R2, out);
}

// Round 12
// 313.670 us; speedup vs baseline: 1.0336x; 1.0130x over previous
//
#include <hip/hip_runtime.h>

typedef __bf16 bf16x8 __attribute__((ext_vector_type(8)));
typedef float  floatx4 __attribute__((ext_vector_type(4)));

constexpr int B_    = 2048;
constexpr int NIN   = 256;
constexpr int H_    = 128;
constexpr int RANK_ = 8;
constexpr float EPS_ = 1e-5f;

// ---------------------------------------------------------------------------
// HEAD: zero stats; lean in_proj (blocks 0..511, 4 rows each, scalar W reads);
// pconv of ALL 8 ranks (unit = bx: rank r = bx>>7, p = bx&127). Grid 1024x256.
__global__ __launch_bounds__(256)
void k_head(const float* __restrict__ X,
            const float* __restrict__ W1, const float* __restrict__ b1,
            const float* __restrict__ W2, const float* __restrict__ b2,
            const float* __restrict__ P,
            float* __restrict__ R2, __bf16* __restrict__ Zbf,
            __bf16* __restrict__ Pperm, float* __restrict__ stats /* 9*256 */) {
    __shared__ float smem[4160];             // sx[1024] / sT[32*129]
    const int bx = blockIdx.x, t = threadIdx.x;

    if (bx < RANK_ + 1) stats[bx * 256 + t] = 0.f;

    if (bx < 512) {   // in_proj rows bx*4 .. +4; thread (col,rh) rows rh, rh+2
        const int b0 = bx * 4;
#pragma unroll
        for (int i = 0; i < 4; ++i) {
            const int e = i * 256 + t;
            smem[e] = X[(size_t)(b0 + (e >> 8)) * NIN + (e & 255)];
        }
        __syncthreads();
        const int col = t & 127, rh = t >> 7;
        float s1a = 0.f, s2a = 0.f, s1b = 0.f, s2b = 0.f;
        const float* sxa = smem + rh * 256;
        const float* sxb = smem + (rh + 2) * 256;
#pragma unroll 8
        for (int i = 0; i < NIN; ++i) {
            const float w1 = W1[i * H_ + col];
            const float w2 = W2[i * H_ + col];
            s1a = fmaf(sxa[i], w1, s1a);  s2a = fmaf(sxa[i], w2, s2a);
            s1b = fmaf(sxb[i], w1, s1b);  s2b = fmaf(sxb[i], w2, s2b);
        }
        const int ba = b0 + rh, bb = b0 + rh + 2;
        const float za = fmaxf(s1a + b1[col], 0.f), ra = fmaxf(s2a + b2[col], 0.f);
        const float zb = fmaxf(s1b + b1[col], 0.f), rb = fmaxf(s2b + b2[col], 0.f);
        Zbf[(size_t)ba * H_ + col] = (__bf16)za;  R2[(size_t)ba * H_ + col] = ra;
        Zbf[(size_t)bb * H_ + col] = (__bf16)zb;  R2[(size_t)bb * H_ + col] = rb;
        __syncthreads();
    }
    {   // pconv: unit = bx -> (rank r, p); fp32 LDS transpose, stride 129
        const int r = bx >> 7, p = bx & 127;
        const float4* Pp4 = (const float4*)(P + ((size_t)r * H_ + p) * (H_ * H_));
        __bf16* dst = Pperm + (size_t)r * (H_ * H_ * H_);
        const int L = t & 63, quad = L >> 4, lo = L & 15, g0 = t >> 6;
#pragma unroll
        for (int s = 0; s < 4; ++s) {
#pragma unroll
            for (int it = 0; it < 4; ++it) {     // 32 q-rows x 128 k, coalesced
                const int idx = it * 256 + t;
                const int q = idx >> 5, k4 = idx & 31;
                const float4 v = Pp4[(size_t)(s * 32 + q) * 32 + k4];
                float* d = smem + q * 129 + k4 * 4;
                d[0] = v.x; d[1] = v.y; d[2] = v.z; d[3] = v.w;
            }
            __syncthreads();
#pragma unroll
            for (int gg = 0; gg < 2; ++gg) {     // conflict-free reads, emit 16B
                const int g = g0 + 4 * gg;
                __bf16 v8[8];
#pragma unroll
                for (int j = 0; j < 8; ++j)
                    v8[j] = (__bf16)smem[(quad * 8 + j) * 129 + g * 16 + lo];
                *(bf16x8*)(dst + (((size_t)(g * 128 + p) * 4 + s) * 64 + L) * 8) =
                    *(const bf16x8*)v8;
            }
            __syncthreads();
        }
    }
}

// ---------------------------------------------------------------------------
// RANK r: T_r = sum_p BNprev(prev)[:,p] * (Zbf @ P_r[p]); stats_r; Y accum.
// Grid (8 kg, 32 m) -> XCD = kg. 512 thr (8 waves), 2 blocks/CU.
// Wave w owns p in [w*16, w*16+16) x all 4 m-tiles; B read once per block.
// First B-frags issued BEFORE the stage barrier (loads to VGPRs cross it).
__global__ __launch_bounds__(512, 2)
void k_rank(const __bf16* __restrict__ Pr, const __bf16* __restrict__ Zbf,
            const float* __restrict__ prevT, const float* __restrict__ prevStats,
            const float* __restrict__ gz, const float* __restrict__ bz,
            float* __restrict__ T, float* __restrict__ stats,
            float* __restrict__ Y, const int ymode) {
    __shared__ float smem[8960];     // sZin[128][68] | reduce[8*1024]+cs; sAl,sBe tail
    const int kg = blockIdx.x, mblk = blockIdx.y, b0 = mblk * 64;
    const int t = threadIdx.x;
    const int w = t >> 6, L = t & 63, quad = L >> 4, lo = L & 15;

    float* sAl = smem + 8704; float* sBe = smem + 8832;
    if (ymode != 0 && t < 128) {
        const float s1 = prevStats[t], s2 = prevStats[128 + t];
        const float mm = s1 * (1.f / B_);
        const float var = s2 * (1.f / B_) - mm * mm;
        const float a = rsqrtf(var + EPS_) * gz[t];
        sAl[t] = a; sBe[t] = bz[t] - mm * a;
    }
    // A-frags: 64 rows x K=128, rank-invariant (64 VGPRs)
    bf16x8 A[4][4];
#pragma unroll
    for (int mt = 0; mt < 4; ++mt)
#pragma unroll
        for (int ks = 0; ks < 4; ++ks)
            A[mt][ks] = *(const bf16x8*)(Zbf + (size_t)(b0 + mt * 16 + lo) * H_ + ks * 32 + quad * 8);

    // prefetch first B-frags (no LDS dependence -> stays in flight across barrier)
    const bf16x8* Pb = (const bf16x8*)Pr;
    const int p0 = w * 16;
    const size_t fbase = ((size_t)kg * 128 + p0) * 4;
    bf16x8 Bf[4], Bn[4];
#pragma unroll
    for (int s = 0; s < 4; ++s) Bf[s] = Pb[(fbase + s) * 64 + L];

    __syncthreads();
    {   // stage zin -> sZin[p][row] (stride 68); Y accum on kg==0
        const int sp = t & 127, rr = t >> 7;     // col, row-quarter
        if (ymode == 0) {
#pragma unroll
            for (int i = 0; i < 16; ++i) {
                const int row = rr + 4 * i;
                smem[sp * 68 + row] = (float)Zbf[(size_t)(b0 + row) * H_ + sp];
            }
        } else {
            const float a = sAl[sp], be = sBe[sp];
#pragma unroll
            for (int i = 0; i < 16; ++i) {
                const int row = rr + 4 * i;
                const float zin = fmaf(prevT[(size_t)(b0 + row) * H_ + sp], a, be);
                smem[sp * 68 + row] = zin;
                if (kg == 0) {
                    float* yp = Y + (size_t)(b0 + row) * H_ + sp;
                    *yp = (ymode == 1) ? zin * (1.f / RANK_) : fmaf(zin, 1.f / RANK_, *yp);
                }
            }
        }
    }
    __syncthreads();

    floatx4 acc[4];
#pragma unroll
    for (int mt = 0; mt < 4; ++mt) acc[mt] = (floatx4){0.f, 0.f, 0.f, 0.f};

    for (int pp = 0; pp < 16; ++pp) {
        const int p = p0 + pp;
        if (pp < 15) {
#pragma unroll
            for (int s = 0; s < 4; ++s)
                Bn[s] = Pb[(fbase + (size_t)(pp + 1) * 4 + s) * 64 + L];
        }
        floatx4 S[4];
#pragma unroll
        for (int mt = 0; mt < 4; ++mt) S[mt] = (floatx4){0.f, 0.f, 0.f, 0.f};
#pragma unroll
        for (int ks = 0; ks < 4; ++ks)
#pragma unroll
            for (int mt = 0; mt < 4; ++mt)
                S[mt] = __builtin_amdgcn_mfma_f32_16x16x32_bf16(A[mt][ks], Bf[ks], S[mt], 0, 0, 0);
#pragma unroll
        for (int mt = 0; mt < 4; ++mt) {
            const floatx4 zi = *(const floatx4*)&smem[p * 68 + mt * 16 + quad * 4];
            acc[mt] += zi * S[mt];
        }
#pragma unroll
        for (int s = 0; s < 4; ++s) Bf[s] = Bn[s];
    }
    __syncthreads();                 // sZin dead; reuse for cross-wave p-reduce
#pragma unroll
    for (int mt = 0; mt < 4; ++mt)
#pragma unroll
        for (int i = 0; i < 4; ++i)
            smem[w * 1024 + (mt * 4 + i) * 64 + L] = acc[mt][i];
    if (t < 32) smem[8192 + t] = 0.f;
    __syncthreads();

    float cs = 0.f, cs2 = 0.f;
#pragma unroll
    for (int k2 = 0; k2 < 2; ++k2) {
        const int e = t + 512 * k2;
        float v = 0.f;
#pragma unroll
        for (int q = 0; q < 8; ++q) v += smem[q * 1024 + e];
        const int j = e >> 6, L2 = e & 63;
        const int row = b0 + (j >> 2) * 16 + (L2 >> 4) * 4 + (j & 3);
        const int col = kg * 16 + (L2 & 15);
        T[(size_t)row * H_ + col] = v;
        cs += v; cs2 += v * v;
    }
    cs  += __shfl_xor(cs, 16);  cs  += __shfl_xor(cs, 32);
    cs2 += __shfl_xor(cs2, 16); cs2 += __shfl_xor(cs2, 32);
    if (L < 16) { atomicAdd(&smem[8192 + L], cs); atomicAdd(&smem[8208 + L], cs2); }
    __syncthreads();
    if (t < 16)      atomicAdd(&stats[kg * 16 + t],            smem[8192 + t]);
    else if (t < 32) atomicAdd(&stats[128 + kg * 16 + t - 16], smem[8192 + t]);
}

// ---------------------------------------------------------------------------
// Y += BN_7(T_7)/8 (finalize); ystats. Grid 64 x 256.
__global__ __launch_bounds__(256)
void k_y(const float* __restrict__ T7, const float* __restrict__ s7,
         const float* __restrict__ gz, const float* __restrict__ bz,
         float* __restrict__ Y, float* __restrict__ ysums) {
    __shared__ float sAl[128], sBe[128], red[256];
    const int bx = blockIdx.x, t = threadIdx.x;
    if (t < 128) {
        const float s1 = s7[t], s2 = s7[128 + t];
        const float mm = s1 * (1.f / B_);
        const float var = s2 * (1.f / B_) - mm * mm;
        const float a = rsqrtf(var + EPS_) * gz[t];
        sAl[t] = a; sBe[t] = bz[t] - mm * a;
    }
    red[t] = 0.f;
    __syncthreads();
    const int col = t & 127, half = t >> 7;
    const float a = sAl[col], be = sBe[col];
    float ps = 0.f, ps2 = 0.f;
    for (int i = 0; i < 16; ++i) {
        const int b = bx * 32 + half + 2 * i;
        const size_t gi = (size_t)b * H_ + col;
        const float y = Y[gi] + fmaf(T7[gi], a, be) * (1.f / RANK_);
        Y[gi] = y;
        ps += y; ps2 += y * y;
    }
    atomicAdd(&red[col],       half == 0 ? ps  : 0.f);
    atomicAdd(&red[128 + col], half == 0 ? ps2 : 0.f);
    __syncthreads();
    atomicAdd(&red[col],       half == 1 ? ps  : 0.f);
    atomicAdd(&red[128 + col], half == 1 ? ps2 : 0.f);
    __syncthreads();
    if (t < 128) {
        atomicAdd(&ysums[t],       red[t]);
        atomicAdd(&ysums[128 + t], red[128 + t]);
    }
}

// ---------------------------------------------------------------------------
// out = relu(relu(BN(Y)@W3 + b3) + R2). Grid 256 x 256, 8 rows per block.
__global__ __launch_bounds__(256)
void k_out(const float* __restrict__ Y, const float* __restrict__ ystats,
           const float* __restrict__ gy, const float* __restrict__ by,
           const float* __restrict__ W3, const float* __restrict__ b3,
           const float* __restrict__ R2, float* __restrict__ out) {
    __shared__ float sy[8 * 132];
    const int bx = blockIdx.x, t = threadIdx.x;
    const int col = t & 127, rh = t >> 7;
    const int b0 = bx * 8;
    const float mm = ystats[col] * (1.f / B_);
    const float var = ystats[128 + col] * (1.f / B_) - mm * mm;
    const float ay = rsqrtf(var + EPS_) * gy[col];
    const float bb = by[col] - mm * ay;
#pragma unroll
    for (int i = 0; i < 4; ++i) {
        const int row = rh + 2 * i;
        sy[row * 132 + col] = fmaf(Y[(size_t)(b0 + row) * H_ + col], ay, bb);
    }
    __syncthreads();
#pragma unroll
    for (int j = 0; j < 4; ++j) {
        const int row = rh * 4 + j;
        float s = 0.f;
        const float* syr = sy + row * 132;
#pragma unroll 8
        for (int h = 0; h < H_; ++h)
            s = fmaf(syr[h], W3[h * H_ + col], s);
        const size_t gi = (size_t)(b0 + row) * H_ + col;
        out[gi] = fmaxf(fmaxf(s + b3[col], 0.f) + R2[gi], 0.f);
    }
}

// ---------------------------------------------------------------------------
extern "C" void kernel_launch(void* const* d_in, const int* in_sizes, int n_in,
                              void* d_out, int out_size, void* d_ws, size_t ws_size,
                              hipStream_t stream) {
    const float* X  = (const float*)d_in[0];
    const float* W1 = (const float*)d_in[1];
    const float* b1 = (const float*)d_in[2];
    const float* W2 = (const float*)d_in[3];
    const float* b2 = (const float*)d_in[4];
    const float* W3 = (const float*)d_in[5];
    const float* b3 = (const float*)d_in[6];
    const float* P  = (const float*)d_in[7];
    const float* gz = (const float*)d_in[8];
    const float* bz = (const float*)d_in[9];
    const float* gy = (const float*)d_in[10];
    const float* by = (const float*)d_in[11];
    float* out = (float*)d_out;

    const size_t rankElems = (size_t)H_ * H_ * H_;

    char* wsb = (char*)d_ws;
    float* R2     = (float*)wsb;   wsb += (size_t)B_ * H_ * 4;
    float* Y      = (float*)wsb;   wsb += (size_t)B_ * H_ * 4;
    float* stats  = (float*)wsb;   wsb += (size_t)(RANK_ + 1) * 256 * 4;  // sums | ysums
    float* T      = (float*)wsb;   wsb += (size_t)RANK_ * B_ * H_ * 4;
    __bf16* Zbf   = (__bf16*)wsb;  wsb += (size_t)B_ * H_ * 2;
    __bf16* Pperm = (__bf16*)wsb;

    float* ysums = stats + RANK_ * 256;

    k_head<<<1024, 256, 0, stream>>>(X, W1, b1, W2, b2, P, R2, Zbf, Pperm, stats);

    for (int r = 0; r < RANK_; ++r) {
        const float* prevT = (r == 0) ? (const float*)Zbf : (T + (size_t)(r - 1) * B_ * H_);
        const float* prevS = (r == 0) ? stats : (stats + (r - 1) * 256);
        const int ymode = (r == 0) ? 0 : (r == 1 ? 1 : 2);
        k_rank<<<dim3(8, 32), 512, 0, stream>>>(Pperm + (size_t)r * rankElems, Zbf,
                                                prevT, prevS, gz, bz,
                                                T + (size_t)r * B_ * H_, stats + r * 256,
                                                Y, ymode);
    }

    k_y<<<64, 256, 0, stream>>>(T + (size_t)7 * B_ * H_, stats + 7 * 256, gz, bz, Y, ysums);
    k_out<<<256, 256, 0, stream>>>(Y, ysums, gy, by, W3, b3, R2, out);
}

// Round 13
// 310.787 us; speedup vs baseline: 1.0432x; 1.0093x over previous
//
#include <hip/hip_runtime.h>

typedef __bf16 bf16x8 __attribute__((ext_vector_type(8)));
typedef float  floatx4 __attribute__((ext_vector_type(4)));

constexpr int B_    = 2048;
constexpr int NIN   = 256;
constexpr int H_    = 128;
constexpr int RANK_ = 8;
constexpr float EPS_ = 1e-5f;

// ---------------------------------------------------------------------------
// HEAD: zero stats; lean in_proj (blocks 0..511, 4 rows each); pconv of ALL
// 8 ranks (unit = bx: rank r = bx>>7, p = bx&127). Grid 1024 x 256.
__global__ __launch_bounds__(256)
void k_head(const float* __restrict__ X,
            const float* __restrict__ W1, const float* __restrict__ b1,
            const float* __restrict__ W2, const float* __restrict__ b2,
            const float* __restrict__ P,
            float* __restrict__ R2, __bf16* __restrict__ Zbf,
            __bf16* __restrict__ Pperm, float* __restrict__ stats /* 9*256 */) {
    __shared__ float smem[4160];             // sx[1024] / sT[32*129]
    const int bx = blockIdx.x, t = threadIdx.x;

    if (bx < RANK_ + 1) stats[bx * 256 + t] = 0.f;

    if (bx < 512) {   // in_proj rows bx*4 .. +4; thread (col,rh) rows rh, rh+2
        const int b0 = bx * 4;
#pragma unroll
        for (int i = 0; i < 4; ++i) {
            const int e = i * 256 + t;
            smem[e] = X[(size_t)(b0 + (e >> 8)) * NIN + (e & 255)];
        }
        __syncthreads();
        const int col = t & 127, rh = t >> 7;
        float s1a = 0.f, s2a = 0.f, s1b = 0.f, s2b = 0.f;
        const float* sxa = smem + rh * 256;
        const float* sxb = smem + (rh + 2) * 256;
#pragma unroll 8
        for (int i = 0; i < NIN; ++i) {
            const float w1 = W1[i * H_ + col];
            const float w2 = W2[i * H_ + col];
            s1a = fmaf(sxa[i], w1, s1a);  s2a = fmaf(sxa[i], w2, s2a);
            s1b = fmaf(sxb[i], w1, s1b);  s2b = fmaf(sxb[i], w2, s2b);
        }
        const int ba = b0 + rh, bb = b0 + rh + 2;
        const float za = fmaxf(s1a + b1[col], 0.f), ra = fmaxf(s2a + b2[col], 0.f);
        const float zb = fmaxf(s1b + b1[col], 0.f), rb = fmaxf(s2b + b2[col], 0.f);
        Zbf[(size_t)ba * H_ + col] = (__bf16)za;  R2[(size_t)ba * H_ + col] = ra;
        Zbf[(size_t)bb * H_ + col] = (__bf16)zb;  R2[(size_t)bb * H_ + col] = rb;
        __syncthreads();
    }
    {   // pconv: unit = bx -> (rank r, p); fp32 LDS transpose, stride 129
        const int r = bx >> 7, p = bx & 127;
        const float4* Pp4 = (const float4*)(P + ((size_t)r * H_ + p) * (H_ * H_));
        __bf16* dst = Pperm + (size_t)r * (H_ * H_ * H_);
        const int L = t & 63, quad = L >> 4, lo = L & 15, g0 = t >> 6;
#pragma unroll
        for (int s = 0; s < 4; ++s) {
#pragma unroll
            for (int it = 0; it < 4; ++it) {     // 32 q-rows x 128 k, coalesced
                const int idx = it * 256 + t;
                const int q = idx >> 5, k4 = idx & 31;
                const float4 v = Pp4[(size_t)(s * 32 + q) * 32 + k4];
                float* d = smem + q * 129 + k4 * 4;
                d[0] = v.x; d[1] = v.y; d[2] = v.z; d[3] = v.w;
            }
            __syncthreads();
#pragma unroll
            for (int gg = 0; gg < 2; ++gg) {     // conflict-free reads, emit 16B
                const int g = g0 + 4 * gg;
                __bf16 v8[8];
#pragma unroll
                for (int j = 0; j < 8; ++j)
                    v8[j] = (__bf16)smem[(quad * 8 + j) * 129 + g * 16 + lo];
                *(bf16x8*)(dst + (((size_t)(g * 128 + p) * 4 + s) * 64 + L) * 8) =
                    *(const bf16x8*)v8;
            }
            __syncthreads();
        }
    }
}

// ---------------------------------------------------------------------------
// RANK r: T_r = sum_p BNprev(prev)[:,p] * (Zbf @ P_r[p]); stats_r; Y accum.
// Grid (8 kg, 64 m) -> XCD = kg. 512 thr (8 waves), M-tile 32,
// __launch_bounds__(512,4) -> 2 blocks/CU, 4 waves/SIMD (phase overlap).
// Wave w owns p in [w*16, w*16+16) x both 16-row tiles; B read once per block.
// Y update distributed: block (kg,m) owns Y[rows, kg*16..+16).
__global__ __launch_bounds__(512, 4)
void k_rank(const __bf16* __restrict__ Pr, const __bf16* __restrict__ Zbf,
            const float* __restrict__ prevT, const float* __restrict__ prevStats,
            const float* __restrict__ gz, const float* __restrict__ bz,
            float* __restrict__ T, float* __restrict__ stats,
            float* __restrict__ Y, const int ymode) {
    __shared__ float smem[4864];     // sZin[128][36]=4608 | reduce[8*512]+cs[32]; sAl/sBe tail
    const int kg = blockIdx.x, mblk = blockIdx.y, b0 = mblk * 32;
    const int t = threadIdx.x;
    const int w = t >> 6, L = t & 63, quad = L >> 4, lo = L & 15;

    float* sAl = smem + 4608; float* sBe = smem + 4736;
    if (ymode != 0 && t < 128) {
        const float s1 = prevStats[t], s2 = prevStats[128 + t];
        const float mm = s1 * (1.f / B_);
        const float var = s2 * (1.f / B_) - mm * mm;
        const float a = rsqrtf(var + EPS_) * gz[t];
        sAl[t] = a; sBe[t] = bz[t] - mm * a;
    }
    // A-frags: 32 rows x K=128, rank-invariant (32 VGPRs)
    bf16x8 A[2][4];
#pragma unroll
    for (int mt = 0; mt < 2; ++mt)
#pragma unroll
        for (int ks = 0; ks < 4; ++ks)
            A[mt][ks] = *(const bf16x8*)(Zbf + (size_t)(b0 + mt * 16 + lo) * H_ + ks * 32 + quad * 8);

    // prefetch first B-frags (VGPR loads cross the barrier)
    const bf16x8* Pb = (const bf16x8*)Pr;
    const int p0 = w * 16;
    const size_t fbase = ((size_t)kg * 128 + p0) * 4;
    bf16x8 Bf[4], Bn[4];
#pragma unroll
    for (int s = 0; s < 4; ++s) Bf[s] = Pb[(fbase + s) * 64 + L];

    __syncthreads();
    {   // stage zin -> sZin[p][row] (stride 36); distributed Y update
        const int sp = t & 127, rr = t >> 7;     // col, row-quarter (0..3)
        const bool doY = (ymode != 0) && ((sp >> 4) == kg);
        if (ymode == 0) {
#pragma unroll
            for (int i = 0; i < 8; ++i) {
                const int row = rr + 4 * i;
                smem[sp * 36 + row] = (float)Zbf[(size_t)(b0 + row) * H_ + sp];
            }
        } else {
            const float a = sAl[sp], be = sBe[sp];
#pragma unroll
            for (int i = 0; i < 8; ++i) {
                const int row = rr + 4 * i;
                const float zin = fmaf(prevT[(size_t)(b0 + row) * H_ + sp], a, be);
                smem[sp * 36 + row] = zin;
                if (doY) {
                    float* yp = Y + (size_t)(b0 + row) * H_ + sp;
                    *yp = (ymode == 1) ? zin * (1.f / RANK_) : fmaf(zin, 1.f / RANK_, *yp);
                }
            }
        }
    }
    __syncthreads();

    floatx4 acc[2];
    acc[0] = (floatx4){0.f, 0.f, 0.f, 0.f};
    acc[1] = (floatx4){0.f, 0.f, 0.f, 0.f};

    for (int pp = 0; pp < 16; ++pp) {
        if (pp < 15) {
#pragma unroll
            for (int s = 0; s < 4; ++s)
                Bn[s] = Pb[(fbase + (size_t)(pp + 1) * 4 + s) * 64 + L];
        }
        floatx4 S[2];
        S[0] = (floatx4){0.f, 0.f, 0.f, 0.f};
        S[1] = (floatx4){0.f, 0.f, 0.f, 0.f};
#pragma unroll
        for (int ks = 0; ks < 4; ++ks)
#pragma unroll
            for (int mt = 0; mt < 2; ++mt)
                S[mt] = __builtin_amdgcn_mfma_f32_16x16x32_bf16(A[mt][ks], Bf[ks], S[mt], 0, 0, 0);
        const int p = p0 + pp;
#pragma unroll
        for (int mt = 0; mt < 2; ++mt) {
            const floatx4 zi = *(const floatx4*)&smem[p * 36 + mt * 16 + quad * 4];
            acc[mt] += zi * S[mt];
        }
#pragma unroll
        for (int s = 0; s < 4; ++s) Bf[s] = Bn[s];
    }
    __syncthreads();                 // sZin dead; reuse for cross-wave p-reduce
#pragma unroll
    for (int mt = 0; mt < 2; ++mt)
#pragma unroll
        for (int i = 0; i < 4; ++i)
            smem[w * 512 + (mt * 4 + i) * 64 + L] = acc[mt][i];
    if (t < 32) smem[4096 + t] = 0.f;
    __syncthreads();

    // one output element per thread
    float v = 0.f;
#pragma unroll
    for (int q = 0; q < 8; ++q) v += smem[q * 512 + t];
    const int j = t >> 6, L2 = t & 63;
    const int row = b0 + (j >> 2) * 16 + (L2 >> 4) * 4 + (j & 3);
    const int col = kg * 16 + (L2 & 15);
    T[(size_t)row * H_ + col] = v;
    float cs = v, cs2 = v * v;
    cs  += __shfl_xor(cs, 16);  cs  += __shfl_xor(cs, 32);
    cs2 += __shfl_xor(cs2, 16); cs2 += __shfl_xor(cs2, 32);
    if (L2 < 16) { atomicAdd(&smem[4096 + L2], cs); atomicAdd(&smem[4112 + L2], cs2); }
    __syncthreads();
    if (t < 16)      atomicAdd(&stats[kg * 16 + t],            smem[4096 + t]);
    else if (t < 32) atomicAdd(&stats[128 + kg * 16 + t - 16], smem[4096 + t]);
}

// ---------------------------------------------------------------------------
// Y += BN_7(T_7)/8 (finalize); ystats. Grid 64 x 256.
__global__ __launch_bounds__(256)
void k_y(const float* __restrict__ T7, const float* __restrict__ s7,
         const float* __restrict__ gz, const float* __restrict__ bz,
         float* __restrict__ Y, float* __restrict__ ysums) {
    __shared__ float sAl[128], sBe[128], red[256];
    const int bx = blockIdx.x, t = threadIdx.x;
    if (t < 128) {
        const float s1 = s7[t], s2 = s7[128 + t];
        const float mm = s1 * (1.f / B_);
        const float var = s2 * (1.f / B_) - mm * mm;
        const float a = rsqrtf(var + EPS_) * gz[t];
        sAl[t] = a; sBe[t] = bz[t] - mm * a;
    }
    red[t] = 0.f;
    __syncthreads();
    const int col = t & 127, half = t >> 7;
    const float a = sAl[col], be = sBe[col];
    float ps = 0.f, ps2 = 0.f;
    for (int i = 0; i < 16; ++i) {
        const int b = bx * 32 + half + 2 * i;
        const size_t gi = (size_t)b * H_ + col;
        const float y = Y[gi] + fmaf(T7[gi], a, be) * (1.f / RANK_);
        Y[gi] = y;
        ps += y; ps2 += y * y;
    }
    atomicAdd(&red[col],       half == 0 ? ps  : 0.f);
    atomicAdd(&red[128 + col], half == 0 ? ps2 : 0.f);
    __syncthreads();
    atomicAdd(&red[col],       half == 1 ? ps  : 0.f);
    atomicAdd(&red[128 + col], half == 1 ? ps2 : 0.f);
    __syncthreads();
    if (t < 128) {
        atomicAdd(&ysums[t],       red[t]);
        atomicAdd(&ysums[128 + t], red[128 + t]);
    }
}

// ---------------------------------------------------------------------------
// out = relu(relu(BN(Y)@W3 + b3) + R2). Grid 256 x 256, 8 rows per block.
__global__ __launch_bounds__(256)
void k_out(const float* __restrict__ Y, const float* __restrict__ ystats,
           const float* __restrict__ gy, const float* __restrict__ by,
           const float* __restrict__ W3, const float* __restrict__ b3,
           const float* __restrict__ R2, float* __restrict__ out) {
    __shared__ float sy[8 * 132];
    const int bx = blockIdx.x, t = threadIdx.x;
    const int col = t & 127, rh = t >> 7;
    const int b0 = bx * 8;
    const float mm = ystats[col] * (1.f / B_);
    const float var = ystats[128 + col] * (1.f / B_) - mm * mm;
    const float ay = rsqrtf(var + EPS_) * gy[col];
    const float bb = by[col] - mm * ay;
#pragma unroll
    for (int i = 0; i < 4; ++i) {
        const int row = rh + 2 * i;
        sy[row * 132 + col] = fmaf(Y[(size_t)(b0 + row) * H_ + col], ay, bb);
    }
    __syncthreads();
#pragma unroll
    for (int j = 0; j < 4; ++j) {
        const int row = rh * 4 + j;
        float s = 0.f;
        const float* syr = sy + row * 132;
#pragma unroll 8
        for (int h = 0; h < H_; ++h)
            s = fmaf(syr[h], W3[h * H_ + col], s);
        const size_t gi = (size_t)(b0 + row) * H_ + col;
        out[gi] = fmaxf(fmaxf(s + b3[col], 0.f) + R2[gi], 0.f);
    }
}

// ---------------------------------------------------------------------------
extern "C" void kernel_launch(void* const* d_in, const int* in_sizes, int n_in,
                              void* d_out, int out_size, void* d_ws, size_t ws_size,
                              hipStream_t stream) {
    const float* X  = (const float*)d_in[0];
    const float* W1 = (const float*)d_in[1];
    const float* b1 = (const float*)d_in[2];
    const float* W2 = (const float*)d_in[3];
    const float* b2 = (const float*)d_in[4];
    const float* W3 = (const float*)d_in[5];
    const float* b3 = (const float*)d_in[6];
    const float* P  = (const float*)d_in[7];
    const float* gz = (const float*)d_in[8];
    const float* bz = (const float*)d_in[9];
    const float* gy = (const float*)d_in[10];
    const float* by = (const float*)d_in[11];
    float* out = (float*)d_out;

    const size_t rankElems = (size_t)H_ * H_ * H_;

    char* wsb = (char*)d_ws;
    float* R2     = (float*)wsb;   wsb += (size_t)B_ * H_ * 4;
    float* Y      = (float*)wsb;   wsb += (size_t)B_ * H_ * 4;
    float* stats  = (float*)wsb;   wsb += (size_t)(RANK_ + 1) * 256 * 4;  // sums | ysums
    float* T      = (float*)wsb;   wsb += (size_t)RANK_ * B_ * H_ * 4;
    __bf16* Zbf   = (__bf16*)wsb;  wsb += (size_t)B_ * H_ * 2;
    __bf16* Pperm = (__bf16*)wsb;

    float* ysums = stats + RANK_ * 256;

    k_head<<<1024, 256, 0, stream>>>(X, W1, b1, W2, b2, P, R2, Zbf, Pperm, stats);

    for (int r = 0; r < RANK_; ++r) {
        const float* prevT = (r == 0) ? (const float*)Zbf : (T + (size_t)(r - 1) * B_ * H_);
        const float* prevS = (r == 0) ? stats : (stats + (r - 1) * 256);
        const int ymode = (r == 0) ? 0 : (r == 1 ? 1 : 2);
        k_rank<<<dim3(8, 64), 512, 0, stream>>>(Pperm + (size_t)r * rankElems, Zbf,
                                                prevT, prevS, gz, bz,
                                                T + (size_t)r * B_ * H_, stats + r * 256,
                                                Y, ymode);
    }

    k_y<<<64, 256, 0, stream>>>(T + (size_t)7 * B_ * H_, stats + 7 * 256, gz, bz, Y, ysums);
    k_out<<<256, 256, 0, stream>>>(Y, ysums, gy, by, W3, b3, R2, out);
}

// Round 14
// 268.400 us; speedup vs baseline: 1.2079x; 1.1579x over previous
//
#include <hip/hip_runtime.h>

typedef __bf16 bf16x8 __attribute__((ext_vector_type(8)));
typedef float  floatx4 __attribute__((ext_vector_type(4)));

constexpr int B_    = 2048;
constexpr int NIN   = 256;
constexpr int H_    = 128;
constexpr int RANK_ = 8;
constexpr float EPS_ = 1e-5f;

// ---------------------------------------------------------------------------
// HEAD: zero stats; lean in_proj (blocks 0..511, 4 rows each); pconv of ALL
// 8 ranks, ALL 16 float4 P-loads issued UP-FRONT (latency hidden behind LDS
// emit of earlier chunks). Grid 1024 x 256.
__global__ __launch_bounds__(256)
void k_head(const float* __restrict__ X,
            const float* __restrict__ W1, const float* __restrict__ b1,
            const float* __restrict__ W2, const float* __restrict__ b2,
            const float* __restrict__ P,
            float* __restrict__ R2, __bf16* __restrict__ Zbf,
            __bf16* __restrict__ Pperm, float* __restrict__ stats /* 9*256 */) {
    __shared__ float smem[4160];             // sx[1024] / sT[32*129]
    const int bx = blockIdx.x, t = threadIdx.x;

    if (bx < RANK_ + 1) stats[bx * 256 + t] = 0.f;

    if (bx < 512) {   // in_proj rows bx*4 .. +4; thread (col,rh) rows rh, rh+2
        const int b0 = bx * 4;
#pragma unroll
        for (int i = 0; i < 4; ++i) {
            const int e = i * 256 + t;
            smem[e] = X[(size_t)(b0 + (e >> 8)) * NIN + (e & 255)];
        }
        __syncthreads();
        const int col = t & 127, rh = t >> 7;
        float s1a = 0.f, s2a = 0.f, s1b = 0.f, s2b = 0.f;
        const float* sxa = smem + rh * 256;
        const float* sxb = smem + (rh + 2) * 256;
#pragma unroll 8
        for (int i = 0; i < NIN; ++i) {
            const float w1 = W1[i * H_ + col];
            const float w2 = W2[i * H_ + col];
            s1a = fmaf(sxa[i], w1, s1a);  s2a = fmaf(sxa[i], w2, s2a);
            s1b = fmaf(sxb[i], w1, s1b);  s2b = fmaf(sxb[i], w2, s2b);
        }
        const int ba = b0 + rh, bb = b0 + rh + 2;
        const float za = fmaxf(s1a + b1[col], 0.f), ra = fmaxf(s2a + b2[col], 0.f);
        const float zb = fmaxf(s1b + b1[col], 0.f), rb = fmaxf(s2b + b2[col], 0.f);
        Zbf[(size_t)ba * H_ + col] = (__bf16)za;  R2[(size_t)ba * H_ + col] = ra;
        Zbf[(size_t)bb * H_ + col] = (__bf16)zb;  R2[(size_t)bb * H_ + col] = rb;
        __syncthreads();
    }
    {   // pconv: unit = bx -> (rank r, p); up-front loads + LDS transpose
        const int r = bx >> 7, p = bx & 127;
        const float4* Pp4 = (const float4*)(P + ((size_t)r * H_ + p) * (H_ * H_));
        __bf16* dst = Pperm + (size_t)r * (H_ * H_ * H_);
        const int L = t & 63, quad = L >> 4, lo = L & 15, g0 = t >> 6;

        float4 rg[4][4];                     // all 16 loads in flight at once
#pragma unroll
        for (int s = 0; s < 4; ++s)
#pragma unroll
            for (int it = 0; it < 4; ++it) {
                const int idx = it * 256 + t;
                rg[s][it] = Pp4[(size_t)(s * 32 + (idx >> 5)) * 32 + (idx & 31)];
            }
#pragma unroll
        for (int s = 0; s < 4; ++s) {
            if (s) __syncthreads();
#pragma unroll
            for (int it = 0; it < 4; ++it) {
                const int idx = it * 256 + t;
                float* d = smem + (idx >> 5) * 129 + (idx & 31) * 4;
                d[0] = rg[s][it].x; d[1] = rg[s][it].y;
                d[2] = rg[s][it].z; d[3] = rg[s][it].w;
            }
            __syncthreads();
#pragma unroll
            for (int gg = 0; gg < 2; ++gg) {  // conflict-free reads, emit 16B
                const int g = g0 + 4 * gg;
                __bf16 v8[8];
#pragma unroll
                for (int j = 0; j < 8; ++j)
                    v8[j] = (__bf16)smem[(quad * 8 + j) * 129 + g * 16 + lo];
                *(bf16x8*)(dst + (((size_t)(g * 128 + p) * 4 + s) * 64 + L) * 8) =
                    *(const bf16x8*)v8;
            }
        }
    }
}

// ---------------------------------------------------------------------------
// RANK r: T_r = sum_p BNprev(prev)[:,p] * (Zbf @ P_r[p]); stats_r.
// Grid (8 kg, 32 m) -> XCD = kg. 512 thr (8 waves), 2 blocks/CU.
// Wave w owns p in [w*16, w*16+16) x all 4 m-tiles; B read once per block.
__global__ __launch_bounds__(512, 2)
void k_rank(const __bf16* __restrict__ Pr, const __bf16* __restrict__ Zbf,
            const float* __restrict__ prevT, const float* __restrict__ prevStats,
            const float* __restrict__ gz, const float* __restrict__ bz,
            float* __restrict__ T, float* __restrict__ stats, const int first) {
    __shared__ float smem[8960];     // sZin[128][68] | reduce[8*1024]+cs; sAl/sBe tail
    const int kg = blockIdx.x, mblk = blockIdx.y, b0 = mblk * 64;
    const int t = threadIdx.x;
    const int w = t >> 6, L = t & 63, quad = L >> 4, lo = L & 15;

    float* sAl = smem + 8704; float* sBe = smem + 8832;
    if (!first && t < 128) {
        const float s1 = prevStats[t], s2 = prevStats[128 + t];
        const float mm = s1 * (1.f / B_);
        const float var = s2 * (1.f / B_) - mm * mm;
        const float a = rsqrtf(var + EPS_) * gz[t];
        sAl[t] = a; sBe[t] = bz[t] - mm * a;
    }
    // A-frags: 64 rows x K=128, rank-invariant (64 VGPRs)
    bf16x8 A[4][4];
#pragma unroll
    for (int mt = 0; mt < 4; ++mt)
#pragma unroll
        for (int ks = 0; ks < 4; ++ks)
            A[mt][ks] = *(const bf16x8*)(Zbf + (size_t)(b0 + mt * 16 + lo) * H_ + ks * 32 + quad * 8);
    __syncthreads();
    {   // stage zin -> sZin[p][row] (stride 68)
        const int sp = t & 127, rr = t >> 7;     // col, row-quarter
        if (first) {
#pragma unroll
            for (int i = 0; i < 16; ++i) {
                const int row = rr + 4 * i;
                smem[sp * 68 + row] = (float)Zbf[(size_t)(b0 + row) * H_ + sp];
            }
        } else {
            const float a = sAl[sp], be = sBe[sp];
#pragma unroll
            for (int i = 0; i < 16; ++i) {
                const int row = rr + 4 * i;
                smem[sp * 68 + row] = fmaf(prevT[(size_t)(b0 + row) * H_ + sp], a, be);
            }
        }
    }
    __syncthreads();

    floatx4 acc[4];
#pragma unroll
    for (int mt = 0; mt < 4; ++mt) acc[mt] = (floatx4){0.f, 0.f, 0.f, 0.f};

    const bf16x8* Pb = (const bf16x8*)Pr;
    const int p0 = w * 16;
    const size_t fbase = ((size_t)kg * 128 + p0) * 4;
    bf16x8 Bf[4], Bn[4];
#pragma unroll
    for (int s = 0; s < 4; ++s) Bf[s] = Pb[(fbase + s) * 64 + L];

    for (int pp = 0; pp < 16; ++pp) {
        const int p = p0 + pp;
        if (pp < 15) {
#pragma unroll
            for (int s = 0; s < 4; ++s)
                Bn[s] = Pb[(fbase + (size_t)(pp + 1) * 4 + s) * 64 + L];
        }
        floatx4 S[4];
#pragma unroll
        for (int mt = 0; mt < 4; ++mt) S[mt] = (floatx4){0.f, 0.f, 0.f, 0.f};
#pragma unroll
        for (int ks = 0; ks < 4; ++ks)
#pragma unroll
            for (int mt = 0; mt < 4; ++mt)
                S[mt] = __builtin_amdgcn_mfma_f32_16x16x32_bf16(A[mt][ks], Bf[ks], S[mt], 0, 0, 0);
#pragma unroll
        for (int mt = 0; mt < 4; ++mt) {
            const floatx4 zi = *(const floatx4*)&smem[p * 68 + mt * 16 + quad * 4];
            acc[mt] += zi * S[mt];
        }
#pragma unroll
        for (int s = 0; s < 4; ++s) Bf[s] = Bn[s];
    }
    __syncthreads();                 // sZin dead; reuse for cross-wave p-reduce
#pragma unroll
    for (int mt = 0; mt < 4; ++mt)
#pragma unroll
        for (int i = 0; i < 4; ++i)
            smem[w * 1024 + (mt * 4 + i) * 64 + L] = acc[mt][i];
    if (t < 32) smem[8192 + t] = 0.f;
    __syncthreads();

    float cs = 0.f, cs2 = 0.f;
#pragma unroll
    for (int k2 = 0; k2 < 2; ++k2) {
        const int e = t + 512 * k2;
        float v = 0.f;
#pragma unroll
        for (int q = 0; q < 8; ++q) v += smem[q * 1024 + e];
        const int j = e >> 6, L2 = e & 63;
        const int row = b0 + (j >> 2) * 16 + (L2 >> 4) * 4 + (j & 3);
        const int col = kg * 16 + (L2 & 15);
        T[(size_t)row * H_ + col] = v;
        cs += v; cs2 += v * v;
    }
    cs  += __shfl_xor(cs, 16);  cs  += __shfl_xor(cs, 32);
    cs2 += __shfl_xor(cs2, 16); cs2 += __shfl_xor(cs2, 32);
    if (L < 16) { atomicAdd(&smem[8192 + L], cs); atomicAdd(&smem[8208 + L], cs2); }
    __syncthreads();
    if (t < 16)      atomicAdd(&stats[kg * 16 + t],            smem[8192 + t]);
    else if (t < 32) atomicAdd(&stats[128 + kg * 16 + t - 16], smem[8192 + t]);
}

// ---------------------------------------------------------------------------
// Y = (1/8) sum_r BN_r(T_r); ystats. Grid 64 x 256.
__global__ __launch_bounds__(256)
void k_y(const float* __restrict__ T, const float* __restrict__ sums,
         const float* __restrict__ gz, const float* __restrict__ bz,
         float* __restrict__ Y, float* __restrict__ ysums) {
    __shared__ float al[1024], be[1024], red[256];
    const int bx = blockIdx.x, t = threadIdx.x;
    for (int e = t; e < 1024; e += 256) {
        const int rr = e >> 7, k = e & 127;
        const float s1 = sums[rr * 256 + k], s2 = sums[rr * 256 + 128 + k];
        const float mm = s1 * (1.f / B_);
        const float var = s2 * (1.f / B_) - mm * mm;
        const float a = rsqrtf(var + EPS_) * gz[k];
        al[e] = a; be[e] = bz[k] - mm * a;
    }
    red[t] = 0.f;
    __syncthreads();
    const int col = t & 127, half = t >> 7;
    float ps = 0.f, ps2 = 0.f;
    for (int i = 0; i < 16; ++i) {
        const int b = bx * 32 + half + 2 * i;
        float y = 0.f;
#pragma unroll
        for (int rr = 0; rr < 8; ++rr)
            y += fmaf(T[(size_t)rr * B_ * H_ + (size_t)b * H_ + col],
                      al[rr * 128 + col], be[rr * 128 + col]);
        y *= (1.f / RANK_);
        Y[(size_t)b * H_ + col] = y;
        ps += y; ps2 += y * y;
    }
    atomicAdd(&red[col],       half == 0 ? ps  : 0.f);
    atomicAdd(&red[128 + col], half == 0 ? ps2 : 0.f);
    __syncthreads();
    atomicAdd(&red[col],       half == 1 ? ps  : 0.f);
    atomicAdd(&red[128 + col], half == 1 ? ps2 : 0.f);
    __syncthreads();
    if (t < 128) {
        atomicAdd(&ysums[t],       red[t]);
        atomicAdd(&ysums[128 + t], red[128 + t]);
    }
}

// ---------------------------------------------------------------------------
// out = relu(relu(BN(Y)@W3 + b3) + R2). Grid 256 x 256, 8 rows per block.
__global__ __launch_bounds__(256)
void k_out(const float* __restrict__ Y, const float* __restrict__ ystats,
           const float* __restrict__ gy, const float* __restrict__ by,
           const float* __restrict__ W3, const float* __restrict__ b3,
           const float* __restrict__ R2, float* __restrict__ out) {
    __shared__ float sy[8 * 132];
    const int bx = blockIdx.x, t = threadIdx.x;
    const int col = t & 127, rh = t >> 7;
    const int b0 = bx * 8;
    const float mm = ystats[col] * (1.f / B_);
    const float var = ystats[128 + col] * (1.f / B_) - mm * mm;
    const float ay = rsqrtf(var + EPS_) * gy[col];
    const float bb = by[col] - mm * ay;
#pragma unroll
    for (int i = 0; i < 4; ++i) {
        const int row = rh + 2 * i;
        sy[row * 132 + col] = fmaf(Y[(size_t)(b0 + row) * H_ + col], ay, bb);
    }
    __syncthreads();
#pragma unroll
    for (int j = 0; j < 4; ++j) {
        const int row = rh * 4 + j;
        float s = 0.f;
        const float* syr = sy + row * 132;
#pragma unroll 8
        for (int h = 0; h < H_; ++h)
            s = fmaf(syr[h], W3[h * H_ + col], s);
        const size_t gi = (size_t)(b0 + row) * H_ + col;
        out[gi] = fmaxf(fmaxf(s + b3[col], 0.f) + R2[gi], 0.f);
    }
}

// ---------------------------------------------------------------------------
extern "C" void kernel_launch(void* const* d_in, const int* in_sizes, int n_in,
                              void* d_out, int out_size, void* d_ws, size_t ws_size,
                              hipStream_t stream) {
    const float* X  = (const float*)d_in[0];
    const float* W1 = (const float*)d_in[1];
    const float* b1 = (const float*)d_in[2];
    const float* W2 = (const float*)d_in[3];
    const float* b2 = (const float*)d_in[4];
    const float* W3 = (const float*)d_in[5];
    const float* b3 = (const float*)d_in[6];
    const float* P  = (const float*)d_in[7];
    const float* gz = (const float*)d_in[8];
    const float* bz = (const float*)d_in[9];
    const float* gy = (const float*)d_in[10];
    const float* by = (const float*)d_in[11];
    float* out = (float*)d_out;

    const size_t rankElems = (size_t)H_ * H_ * H_;

    char* wsb = (char*)d_ws;
    float* R2     = (float*)wsb;   wsb += (size_t)B_ * H_ * 4;
    float* Y      = (float*)wsb;   wsb += (size_t)B_ * H_ * 4;
    float* stats  = (float*)wsb;   wsb += (size_t)(RANK_ + 1) * 256 * 4;  // sums | ysums
    float* T      = (float*)wsb;   wsb += (size_t)RANK_ * B_ * H_ * 4;
    __bf16* Zbf   = (__bf16*)wsb;  wsb += (size_t)B_ * H_ * 2;
    __bf16* Pperm = (__bf16*)wsb;

    float* ysums = stats + RANK_ * 256;

    k_head<<<1024, 256, 0, stream>>>(X, W1, b1, W2, b2, P, R2, Zbf, Pperm, stats);

    for (int r = 0; r < RANK_; ++r) {
        const float* prevT = (r == 0) ? (const float*)Zbf : (T + (size_t)(r - 1) * B_ * H_);
        const float* prevS = (r == 0) ? stats : (stats + (r - 1) * 256);
        k_rank<<<dim3(8, 32), 512, 0, stream>>>(Pperm + (size_t)r * rankElems, Zbf,
                                                prevT, prevS, gz, bz,
                                                T + (size_t)r * B_ * H_, stats + r * 256,
                                                r == 0 ? 1 : 0);
    }

    k_y<<<64, 256, 0, stream>>>(T, stats, gz, bz, Y, ysums);
    k_out<<<256, 256, 0, stream>>>(Y, ysums, gy, by, W3, b3, R2, out);
}